// Round 1
// baseline (439.161 us; speedup 1.0000x reference)
//
#include <hip/hip_runtime.h>

// ---------------------------------------------------------------------------
// Fused MHA block on gfx950, fp16 MFMA pipeline.
//   qkv GEMM (16384x2304x768) -> per-head flash attention (192 x 1024x1024x64)
//   -> proj GEMM (16384x768x768)
// All matmuls via v_mfma_f32_16x16x32_f16 (fp32 accumulate).
// ---------------------------------------------------------------------------

typedef _Float16 half8 __attribute__((ext_vector_type(8)));
typedef _Float16 half4 __attribute__((ext_vector_type(4)));
typedef float    f32x4 __attribute__((ext_vector_type(4)));
typedef unsigned int u32x4 __attribute__((ext_vector_type(4)));

#define DI __device__ __forceinline__

constexpr int   BATCH  = 16;
constexpr int   SEQ    = 1024;
constexpr int   DM     = 768;
constexpr int   NH     = 12;
constexpr int   HD     = 64;
constexpr int   MROWS  = BATCH * SEQ;     // 16384
constexpr float SCALE  = 0.125f;          // 1/sqrt(64)
constexpr float LOG2E  = 1.4426950408889634f;

// async global->LDS, 16B per lane (dest must be wave-uniform base + lane*16)
DI void async16(const _Float16* g, _Float16* l) {
  __builtin_amdgcn_global_load_lds(
      (const __attribute__((address_space(1))) void*)g,
      (__attribute__((address_space(3))) void*)l, 16, 0, 0);
}

DI void copy16(_Float16* dst, const _Float16* src) {
  *(u32x4*)dst = *(const u32x4*)src;
}

// ---------------------------------------------------------------------------
// converts
// ---------------------------------------------------------------------------
__global__ void cvt_x_kernel(const float* __restrict__ x,
                             _Float16* __restrict__ xh, int n4) {
  int i = blockIdx.x * 256 + threadIdx.x;
  if (i >= n4) return;
  float4 v = ((const float4*)x)[i];
  half4 h;
  h[0] = (_Float16)v.x; h[1] = (_Float16)v.y;
  h[2] = (_Float16)v.z; h[3] = (_Float16)v.w;
  *(half4*)(xh + (size_t)i * 4) = h;
}

// wt[n*K + k] = w[k*N + n]  (store W^T so GEMM B-frags are contiguous in k)
__global__ void cvt_wt_kernel(const float* __restrict__ w,
                              _Float16* __restrict__ wt, int K, int N) {
  int idx = blockIdx.x * 256 + threadIdx.x;
  if (idx >= K * N) return;
  int k = idx % K, n = idx / K;
  wt[idx] = (_Float16)w[(size_t)k * N + n];
}

// ---------------------------------------------------------------------------
// GEMM1: qkv = xh[16384x768] @ wqkvT^T + bias, scatter epilogue into
//   Q[bh][n][d], K[bh][n][d], VT[bh][d][n]  (fp16)
// ---------------------------------------------------------------------------
__launch_bounds__(256)
__global__ void gemm_qkv_kernel(const _Float16* __restrict__ A,
                                const _Float16* __restrict__ Bt,
                                const float* __restrict__ bias,
                                _Float16* __restrict__ Qo,
                                _Float16* __restrict__ Ko,
                                _Float16* __restrict__ VTo) {
  __shared__ _Float16 As[128 * 32];
  __shared__ _Float16 Bs[128 * 32];
  __shared__ _Float16 Cs[128 * 136];   // padded stride 136 breaks bank alignment
  const int tid  = threadIdx.x;
  const int ct   = blockIdx.x;        // 0..17 col tiles
  const int m0   = blockIdx.y * 128;
  const int n0   = ct * 128;
  const int w    = tid >> 6, lane = tid & 63;
  const int quad = lane >> 4, l15 = lane & 15;
  const int wr   = w >> 1, wc = w & 1;

  f32x4 acc[4][4] = {};

  const int e  = tid * 8;        // element offset of this thread's 16B stage
  const int rA = e >> 5;         // row 0..63 (second call does +64)
  const int kA = e & 31;
  const _Float16* ga = A  + (size_t)(m0 + rA) * 768 + kA;
  const _Float16* gb = Bt + (size_t)(n0 + rA) * 768 + kA;

  for (int kt = 0; kt < 24; ++kt) {
    __syncthreads();
    const int k0 = kt * 32;
    async16(ga + k0,            &As[e]);
    async16(ga + k0 + 64 * 768, &As[e + 2048]);
    async16(gb + k0,            &Bs[e]);
    async16(gb + k0 + 64 * 768, &Bs[e + 2048]);
    __syncthreads();

    half8 af[4], bf[4];
#pragma unroll
    for (int mi = 0; mi < 4; mi++)
      af[mi] = *(const half8*)&As[(wr * 64 + mi * 16 + l15) * 32 + quad * 8];
#pragma unroll
    for (int ni = 0; ni < 4; ni++)
      bf[ni] = *(const half8*)&Bs[(wc * 64 + ni * 16 + l15) * 32 + quad * 8];
#pragma unroll
    for (int mi = 0; mi < 4; mi++)
#pragma unroll
      for (int ni = 0; ni < 4; ni++)
        acc[mi][ni] = __builtin_amdgcn_mfma_f32_16x16x32_f16(
            af[mi], bf[ni], acc[mi][ni], 0, 0, 0);
  }

  // bias + fp16 convert -> Cs
  float bcol[4];
#pragma unroll
  for (int ni = 0; ni < 4; ni++)
    bcol[ni] = bias[n0 + wc * 64 + ni * 16 + l15];
#pragma unroll
  for (int mi = 0; mi < 4; mi++)
#pragma unroll
    for (int ni = 0; ni < 4; ni++) {
      int col = wc * 64 + ni * 16 + l15;
      int row = wr * 64 + mi * 16 + quad * 4;
#pragma unroll
      for (int r = 0; r < 4; r++)
        Cs[(row + r) * 136 + col] = (_Float16)(acc[mi][ni][r] + bcol[ni]);
    }
  __syncthreads();

  const int b     = m0 >> 10;          // tile lies within one batch (1024/128=8)
  const int nrow0 = m0 & 1023;
  const int sec   = ct / 6;            // 0=Q 1=K 2=V
  const int h0    = (ct % 6) * 2;      // two heads per 128-col tile

  if (sec < 2) {
    _Float16* dst = (sec == 0) ? Qo : Ko;
    int r = tid >> 1, hl = tid & 1;
    _Float16* g = dst + ((size_t)((b * NH + h0 + hl) * SEQ + nrow0 + r)) * HD;
    const _Float16* s = &Cs[r * 136 + hl * 64];
#pragma unroll
    for (int j = 0; j < 8; j++) copy16(g + j * 8, s + j * 8);
  } else {
    int c = tid >> 1, hf = tid & 1;    // c = tile col 0..127, hf = row half
    int hl = c >> 6, d = c & 63;
    _Float16 tmp[64];
#pragma unroll
    for (int j = 0; j < 64; j++) tmp[j] = Cs[(hf * 64 + j) * 136 + c];
    _Float16* g = VTo + ((size_t)((b * NH + h0 + hl) * HD + d)) * SEQ
                      + nrow0 + hf * 64;
#pragma unroll
    for (int j = 0; j < 8; j++) copy16(g + j * 8, (const _Float16*)&tmp[j * 8]);
  }
}

// ---------------------------------------------------------------------------
// Flash attention: one wg = (bh, 64-row Q tile); K-tiles of 128.
// ---------------------------------------------------------------------------
__launch_bounds__(256)
__global__ void attn_kernel(const _Float16* __restrict__ Q,
                            const _Float16* __restrict__ K,
                            const _Float16* __restrict__ VT,
                            _Float16* __restrict__ Oh) {
  __shared__ _Float16 Qs[64 * 72];     // padded stride 72 (b128 reads 2-way free)
  __shared__ _Float16 Ks[128 * 72];
  __shared__ _Float16 VTs[64 * 136];
  __shared__ _Float16 Ps[64 * 136];
  const int tid  = threadIdx.x;
  const int bh   = blockIdx.y;
  const int b    = bh / NH, h = bh - b * NH;
  const int q0   = blockIdx.x * 64;
  const int w    = tid >> 6, lane = tid & 63;
  const int quad = lane >> 4, l15 = lane & 15;

  const _Float16* Qg = Q  + ((size_t)bh * SEQ + q0) * HD;
  const _Float16* Kg = K  + (size_t)bh * SEQ * HD;
  const _Float16* Vg = VT + (size_t)bh * HD * SEQ;

  { // stage Q tile once
    int r = tid >> 2, s4 = tid & 3;
    copy16(&Qs[r * 72 + s4 * 16],     Qg + r * 64 + s4 * 16);
    copy16(&Qs[r * 72 + s4 * 16 + 8], Qg + r * 64 + s4 * 16 + 8);
  }

  f32x4 of[4] = {};
  float mrow[4], lrow[4];
#pragma unroll
  for (int r = 0; r < 4; r++) { mrow[r] = -3.0e38f; lrow[r] = 0.f; }

  for (int kt = 0; kt < 8; ++kt) {
    if (kt) __syncthreads();           // protect Ks/VTs reuse
    { // stage K tile [128][64] -> Ks[128][72]
      int r = tid >> 1, hf = tid & 1;
      const _Float16* src = Kg + (size_t)(kt * 128 + r) * 64 + hf * 32;
      _Float16* dst = &Ks[r * 72 + hf * 32];
#pragma unroll
      for (int j = 0; j < 4; j++) copy16(dst + j * 8, src + j * 8);
    }
    { // stage V^T tile [64][128] -> VTs[64][136]
      int d = tid >> 2, p4 = tid & 3;
      const _Float16* src = Vg + (size_t)d * SEQ + kt * 128 + p4 * 32;
      _Float16* dst = &VTs[d * 136 + p4 * 32];
#pragma unroll
      for (int j = 0; j < 4; j++) copy16(dst + j * 8, src + j * 8);
    }
    __syncthreads();

    // S = Q K^T : wave owns 16 q-rows x 128 cols
    half8 aq[2];
#pragma unroll
    for (int ks = 0; ks < 2; ks++)
      aq[ks] = *(const half8*)&Qs[(w * 16 + l15) * 72 + ks * 32 + quad * 8];
    f32x4 sf[8] = {};
#pragma unroll
    for (int n = 0; n < 8; n++)
#pragma unroll
      for (int ks = 0; ks < 2; ks++) {
        half8 bk = *(const half8*)&Ks[(n * 16 + l15) * 72 + ks * 32 + quad * 8];
        sf[n] = __builtin_amdgcn_mfma_f32_16x16x32_f16(aq[ks], bk, sf[n], 0, 0, 0);
      }
#pragma unroll
    for (int n = 0; n < 8; n++)
#pragma unroll
      for (int r = 0; r < 4; r++) sf[n][r] *= SCALE;

    // online softmax over rows (row = quad*4+r, cols across 16 lanes of quad)
    float tmax[4];
#pragma unroll
    for (int r = 0; r < 4; r++) tmax[r] = -3.0e38f;
#pragma unroll
    for (int n = 0; n < 8; n++)
#pragma unroll
      for (int r = 0; r < 4; r++) tmax[r] = fmaxf(tmax[r], sf[n][r]);
#pragma unroll
    for (int off = 1; off < 16; off <<= 1)
#pragma unroll
      for (int r = 0; r < 4; r++)
        tmax[r] = fmaxf(tmax[r], __shfl_xor(tmax[r], off, 64));

    float alpha[4], tsum[4];
#pragma unroll
    for (int r = 0; r < 4; r++) {
      float mnew = fmaxf(mrow[r], tmax[r]);
      alpha[r] = exp2f((mrow[r] - mnew) * LOG2E);
      mrow[r] = mnew;
      tsum[r] = 0.f;
    }
#pragma unroll
    for (int n = 0; n < 8; n++)
#pragma unroll
      for (int r = 0; r < 4; r++) {
        float p = exp2f((sf[n][r] - mrow[r]) * LOG2E);
        tsum[r] += p;
        Ps[(w * 16 + quad * 4 + r) * 136 + n * 16 + l15] = (_Float16)p;
      }
#pragma unroll
    for (int off = 1; off < 16; off <<= 1)
#pragma unroll
      for (int r = 0; r < 4; r++) tsum[r] += __shfl_xor(tsum[r], off, 64);
#pragma unroll
    for (int r = 0; r < 4; r++) lrow[r] = lrow[r] * alpha[r] + tsum[r];
#pragma unroll
    for (int nd = 0; nd < 4; nd++)
#pragma unroll
      for (int r = 0; r < 4; r++) of[nd][r] *= alpha[r];

    // O += P V   (wave reads only its own 16 Ps rows -> no barrier needed)
#pragma unroll
    for (int kks = 0; kks < 4; kks++) {
      half8 ap = *(const half8*)&Ps[(w * 16 + l15) * 136 + kks * 32 + quad * 8];
#pragma unroll
      for (int nd = 0; nd < 4; nd++) {
        half8 bv = *(const half8*)&VTs[(nd * 16 + l15) * 136 + kks * 32 + quad * 8];
        of[nd] = __builtin_amdgcn_mfma_f32_16x16x32_f16(ap, bv, of[nd], 0, 0, 0);
      }
    }
  }

  // normalize, stage through Ps, coalesced store to Oh[(b*SEQ+n)][DM]
#pragma unroll
  for (int r = 0; r < 4; r++) {
    float inv = 1.0f / lrow[r];
#pragma unroll
    for (int nd = 0; nd < 4; nd++) of[nd][r] *= inv;
  }
#pragma unroll
  for (int nd = 0; nd < 4; nd++)
#pragma unroll
    for (int r = 0; r < 4; r++)
      Ps[(w * 16 + quad * 4 + r) * 136 + nd * 16 + l15] = (_Float16)of[nd][r];
  __syncthreads();
  {
    int r = tid >> 2, p4 = tid & 3;
    _Float16* g = Oh + ((size_t)(b * SEQ + q0 + r)) * DM + h * HD + p4 * 16;
    const _Float16* s = &Ps[r * 136 + p4 * 16];
    copy16(g, s);
    copy16(g + 8, s + 8);
  }
}

// ---------------------------------------------------------------------------
// GEMM2: out = Oh[16384x768] @ wprojT^T + bias  (fp32 direct stores)
// ---------------------------------------------------------------------------
__launch_bounds__(256)
__global__ void gemm_proj_kernel(const _Float16* __restrict__ A,
                                 const _Float16* __restrict__ Bt,
                                 const float* __restrict__ bias,
                                 float* __restrict__ out) {
  __shared__ _Float16 As[128 * 32];
  __shared__ _Float16 Bs[128 * 32];
  const int tid  = threadIdx.x;
  const int m0   = blockIdx.y * 128;
  const int n0   = blockIdx.x * 128;
  const int w    = tid >> 6, lane = tid & 63;
  const int quad = lane >> 4, l15 = lane & 15;
  const int wr   = w >> 1, wc = w & 1;

  f32x4 acc[4][4] = {};

  const int e  = tid * 8;
  const int rA = e >> 5;
  const int kA = e & 31;
  const _Float16* ga = A  + (size_t)(m0 + rA) * 768 + kA;
  const _Float16* gb = Bt + (size_t)(n0 + rA) * 768 + kA;

  for (int kt = 0; kt < 24; ++kt) {
    __syncthreads();
    const int k0 = kt * 32;
    async16(ga + k0,            &As[e]);
    async16(ga + k0 + 64 * 768, &As[e + 2048]);
    async16(gb + k0,            &Bs[e]);
    async16(gb + k0 + 64 * 768, &Bs[e + 2048]);
    __syncthreads();

    half8 af[4], bf[4];
#pragma unroll
    for (int mi = 0; mi < 4; mi++)
      af[mi] = *(const half8*)&As[(wr * 64 + mi * 16 + l15) * 32 + quad * 8];
#pragma unroll
    for (int ni = 0; ni < 4; ni++)
      bf[ni] = *(const half8*)&Bs[(wc * 64 + ni * 16 + l15) * 32 + quad * 8];
#pragma unroll
    for (int mi = 0; mi < 4; mi++)
#pragma unroll
      for (int ni = 0; ni < 4; ni++)
        acc[mi][ni] = __builtin_amdgcn_mfma_f32_16x16x32_f16(
            af[mi], bf[ni], acc[mi][ni], 0, 0, 0);
  }

  float bcol[4];
#pragma unroll
  for (int ni = 0; ni < 4; ni++)
    bcol[ni] = bias[n0 + wc * 64 + ni * 16 + l15];
#pragma unroll
  for (int mi = 0; mi < 4; mi++)
#pragma unroll
    for (int ni = 0; ni < 4; ni++) {
      int col = n0 + wc * 64 + ni * 16 + l15;
      int row = m0 + wr * 64 + mi * 16 + quad * 4;
#pragma unroll
      for (int r = 0; r < 4; r++)
        out[(size_t)(row + r) * 768 + col] = acc[mi][ni][r] + bcol[ni];
    }
}

// ---------------------------------------------------------------------------
// launch
// ---------------------------------------------------------------------------
extern "C" void kernel_launch(void* const* d_in, const int* in_sizes, int n_in,
                              void* d_out, int out_size, void* d_ws, size_t ws_size,
                              hipStream_t stream) {
  const float* x      = (const float*)d_in[0];
  const float* w_qkv  = (const float*)d_in[1];
  const float* b_qkv  = (const float*)d_in[2];
  const float* w_proj = (const float*)d_in[3];
  const float* b_proj = (const float*)d_in[4];
  float* out = (float*)d_out;

  char* ws = (char*)d_ws;
  // fp16 workspace layout (bytes):
  _Float16* xh     = (_Float16*)(ws);                 //  16384*768       = 25165824 B
  _Float16* wqkvT  = (_Float16*)(ws + 25165824);      //  2304*768       ->  3538944 B
  _Float16* wprojT = (_Float16*)(ws + 28704768);      //   768*768       ->  1179648 B
  _Float16* Qp     = (_Float16*)(ws + 29884416);      //  192*1024*64    -> 25165824 B
  _Float16* Kp     = (_Float16*)(ws + 55050240);      //  192*1024*64    -> 25165824 B
  _Float16* VTp    = (_Float16*)(ws + 80216064);      //  192*64*1024    -> 25165824 B
  _Float16* Ohp    = (_Float16*)(ws + 105381888);     //  16384*768      -> 25165824 B
  // total: 130547712 B (~125 MB)

  cvt_x_kernel<<<dim3(3145728 / 256), 256, 0, stream>>>(x, xh, 3145728);
  cvt_wt_kernel<<<dim3((768 * 2304) / 256), 256, 0, stream>>>(w_qkv, wqkvT, 768, 2304);
  cvt_wt_kernel<<<dim3((768 * 768) / 256), 256, 0, stream>>>(w_proj, wprojT, 768, 768);
  gemm_qkv_kernel<<<dim3(18, 128), 256, 0, stream>>>(xh, wqkvT, b_qkv, Qp, Kp, VTp);
  attn_kernel<<<dim3(16, 192), 256, 0, stream>>>(Qp, Kp, VTp, Ohp);
  gemm_proj_kernel<<<dim3(6, 128), 256, 0, stream>>>(Ohp, wprojT, b_proj, out);
}

// Round 3
// 321.236 us; speedup vs baseline: 1.3671x; 1.3671x over previous
//
#include <hip/hip_runtime.h>

// ---------------------------------------------------------------------------
// Fused MHA block on gfx950, fp16 MFMA pipeline.
//   qkv GEMM (16384x2304x768) -> per-head flash attention (192 x 1024x1024x64)
//   -> proj GEMM (16384x768x768)
// GEMMs: v_mfma_f32_16x16x32_f16.  Attention: v_mfma_f32_32x32x16_f16 in
// TRANSPOSED orientation (S^T = K Q^T, O^T = V^T P^T) so P stays in registers.
// ---------------------------------------------------------------------------

typedef _Float16 half8 __attribute__((ext_vector_type(8)));
typedef _Float16 half4 __attribute__((ext_vector_type(4)));
typedef __fp16   fp16x2 __attribute__((ext_vector_type(2)));
typedef float    f32x4  __attribute__((ext_vector_type(4)));
typedef float    f32x16 __attribute__((ext_vector_type(16)));
typedef unsigned int u32x4 __attribute__((ext_vector_type(4)));

#define DI __device__ __forceinline__

constexpr int   BATCH  = 16;
constexpr int   SEQ    = 1024;
constexpr int   DM     = 768;
constexpr int   NH     = 12;
constexpr int   HD     = 64;
constexpr float SCALE  = 0.125f;          // 1/sqrt(64), folded into Q epilogue
constexpr float LOG2E  = 1.4426950408889634f;

// async global->LDS, 16B per lane (dest must be wave-uniform base + lane*16)
DI void async16(const _Float16* g, _Float16* l) {
  __builtin_amdgcn_global_load_lds(
      (const __attribute__((address_space(1))) void*)g,
      (__attribute__((address_space(3))) void*)l, 16, 0, 0);
}

DI void copy16(_Float16* dst, const _Float16* src) {
  *(u32x4*)dst = *(const u32x4*)src;
}

DI int pack_rtz(float a, float b) {
  union { fp16x2 h; int i; } u;
  u.h = __builtin_amdgcn_cvt_pkrtz(a, b);
  return u.i;
}

// ---------------------------------------------------------------------------
// converts
// ---------------------------------------------------------------------------
__global__ void cvt_x_kernel(const float* __restrict__ x,
                             _Float16* __restrict__ xh, int n4) {
  int i = blockIdx.x * 256 + threadIdx.x;
  if (i >= n4) return;
  float4 v = ((const float4*)x)[i];
  half4 h;
  h[0] = (_Float16)v.x; h[1] = (_Float16)v.y;
  h[2] = (_Float16)v.z; h[3] = (_Float16)v.w;
  *(half4*)(xh + (size_t)i * 4) = h;
}

// wt[n*K + k] = w[k*N + n], coalesced via 32x32 LDS tile
__global__ void cvt_wt_kernel(const float* __restrict__ w,
                              _Float16* __restrict__ wt, int K, int N) {
  __shared__ float tile[32][33];
  int kb = blockIdx.x * 32, nb = blockIdx.y * 32;
  int tx = threadIdx.x & 31, ty = threadIdx.x >> 5;   // ty 0..7
#pragma unroll
  for (int i = 0; i < 32; i += 8)
    tile[ty + i][tx] = w[(size_t)(kb + ty + i) * N + nb + tx];
  __syncthreads();
#pragma unroll
  for (int i = 0; i < 32; i += 8)
    wt[(size_t)(nb + ty + i) * K + kb + tx] = (_Float16)tile[tx][ty + i];
}

// ---------------------------------------------------------------------------
// GEMM1: qkv = xh[16384x768] @ wqkvT^T + bias, scatter epilogue into
//   Q[bh][n][d] (prescaled by 0.125), K[bh][n][d], VT[bh][d][n]  (fp16)
// ---------------------------------------------------------------------------
__launch_bounds__(256)
__global__ void gemm_qkv_kernel(const _Float16* __restrict__ A,
                                const _Float16* __restrict__ Bt,
                                const float* __restrict__ bias,
                                _Float16* __restrict__ Qo,
                                _Float16* __restrict__ Ko,
                                _Float16* __restrict__ VTo) {
  __shared__ _Float16 As[128 * 32];
  __shared__ _Float16 Bs[128 * 32];
  __shared__ _Float16 Cs[128 * 136];
  const int tid  = threadIdx.x;
  const int ct   = blockIdx.x;        // 0..17 col tiles
  const int m0   = blockIdx.y * 128;
  const int n0   = ct * 128;
  const int w    = tid >> 6, lane = tid & 63;
  const int quad = lane >> 4, l15 = lane & 15;
  const int wr   = w >> 1, wc = w & 1;

  f32x4 acc[4][4] = {};

  const int e  = tid * 8;
  const int rA = e >> 5;
  const int kA = e & 31;
  const _Float16* ga = A  + (size_t)(m0 + rA) * 768 + kA;
  const _Float16* gb = Bt + (size_t)(n0 + rA) * 768 + kA;

  for (int kt = 0; kt < 24; ++kt) {
    __syncthreads();
    const int k0 = kt * 32;
    async16(ga + k0,            &As[e]);
    async16(ga + k0 + 64 * 768, &As[e + 2048]);
    async16(gb + k0,            &Bs[e]);
    async16(gb + k0 + 64 * 768, &Bs[e + 2048]);
    __syncthreads();

    half8 af[4], bf[4];
#pragma unroll
    for (int mi = 0; mi < 4; mi++)
      af[mi] = *(const half8*)&As[(wr * 64 + mi * 16 + l15) * 32 + quad * 8];
#pragma unroll
    for (int ni = 0; ni < 4; ni++)
      bf[ni] = *(const half8*)&Bs[(wc * 64 + ni * 16 + l15) * 32 + quad * 8];
#pragma unroll
    for (int mi = 0; mi < 4; mi++)
#pragma unroll
      for (int ni = 0; ni < 4; ni++)
        acc[mi][ni] = __builtin_amdgcn_mfma_f32_16x16x32_f16(
            af[mi], bf[ni], acc[mi][ni], 0, 0, 0);
  }

  // bias (+Q prescale) + fp16 convert -> Cs
  const float oscale = (ct < 6) ? SCALE : 1.0f;
  float bcol[4];
#pragma unroll
  for (int ni = 0; ni < 4; ni++)
    bcol[ni] = bias[n0 + wc * 64 + ni * 16 + l15];
#pragma unroll
  for (int mi = 0; mi < 4; mi++)
#pragma unroll
    for (int ni = 0; ni < 4; ni++) {
      int col = wc * 64 + ni * 16 + l15;
      int row = wr * 64 + mi * 16 + quad * 4;
#pragma unroll
      for (int r = 0; r < 4; r++)
        Cs[(row + r) * 136 + col] = (_Float16)((acc[mi][ni][r] + bcol[ni]) * oscale);
    }
  __syncthreads();

  const int b     = m0 >> 10;
  const int nrow0 = m0 & 1023;
  const int sec   = ct / 6;            // 0=Q 1=K 2=V
  const int h0    = (ct % 6) * 2;

  if (sec < 2) {
    _Float16* dst = (sec == 0) ? Qo : Ko;
    int r = tid >> 1, hl = tid & 1;
    _Float16* g = dst + ((size_t)((b * NH + h0 + hl) * SEQ + nrow0 + r)) * HD;
    const _Float16* s = &Cs[r * 136 + hl * 64];
#pragma unroll
    for (int j = 0; j < 8; j++) copy16(g + j * 8, s + j * 8);
  } else {
    int c = tid >> 1, hf = tid & 1;
    int hl = c >> 6, d = c & 63;
    _Float16 tmp[64];
#pragma unroll
    for (int j = 0; j < 64; j++) tmp[j] = Cs[(hf * 64 + j) * 136 + c];
    _Float16* g = VTo + ((size_t)((b * NH + h0 + hl) * HD + d)) * SEQ
                      + nrow0 + hf * 64;
#pragma unroll
    for (int j = 0; j < 8; j++) copy16(g + j * 8, (const _Float16*)&tmp[j * 8]);
  }
}

// ---------------------------------------------------------------------------
// Flash attention, transposed: one wg = (bh, 256-q tile), 4 waves x 64 q.
// S^T = K Q^T (32x32x16 MFMA), P^T kept in registers via half-swap shuffles,
// O^T = V^T P^T.  K-tile 64, double-buffered LDS staging.
// ---------------------------------------------------------------------------
__launch_bounds__(256, 2)
__global__ void attn_kernel(const _Float16* __restrict__ Q,
                            const _Float16* __restrict__ K,
                            const _Float16* __restrict__ VT,
                            _Float16* __restrict__ Oh) {
  __shared__ _Float16 smem[2][2][64 * 72];   // [buf][K/V][64 rows][72]
  _Float16* OLds = &smem[0][0][0];           // aliased epilogue staging (36864B)

  const int tid = threadIdx.x;
  const int i   = blockIdx.x;
  const int bh  = (i & 7) * 24 + ((i >> 3) >> 2);   // XCD swizzle: 4 q-blocks
  const int q0  = ((i >> 3) & 3) * 256;             //  of one bh share an XCD
  const int b   = bh / NH, hh = bh - b * NH;
  const int w   = tid >> 6, lane = tid & 63;
  const int l31 = lane & 31, h = lane >> 5;

  const _Float16* Qg = Q  + (size_t)bh * SEQ * HD;
  const _Float16* Kg = K  + (size_t)bh * SEQ * HD;
  const _Float16* Vg = VT + (size_t)bh * HD * SEQ;

  // persistent Q B-frags: qb[N][s] ; B[k=d][n=q] read from Q[q][d] row-major
  half8 qb[2][4];
#pragma unroll
  for (int N = 0; N < 2; N++) {
    const _Float16* qrow = Qg + (size_t)(q0 + w * 64 + N * 32 + l31) * HD + h * 8;
#pragma unroll
    for (int s = 0; s < 4; s++)
      qb[N][s] = *(const half8*)(qrow + s * 16);
  }

  // staging: threads 0-127 stage K tile, 128-255 stage V^T tile (64B each)
  const int  sr  = (tid & 127) >> 1;
  const int  sp  = tid & 1;
  const bool isK = tid < 128;
  const _Float16* sg = isK ? (Kg + sr * HD + sp * 32)
                           : (Vg + (size_t)sr * SEQ + sp * 32);
  const int sstep = isK ? 64 * HD : 64;
  const int soff  = (isK ? 0 : 64 * 72) + sr * 72 + sp * 32;

  u32x4 pf[4];
#pragma unroll
  for (int c = 0; c < 4; c++) pf[c] = *(const u32x4*)(sg + c * 8);
#pragma unroll
  for (int c = 0; c < 4; c++) *(u32x4*)(&smem[0][0][0] + soff + c * 8) = pf[c];

  f32x16 of[2][2];
#pragma unroll
  for (int D = 0; D < 2; D++)
#pragma unroll
    for (int N = 0; N < 2; N++)
#pragma unroll
      for (int r = 0; r < 16; r++) of[D][N][r] = 0.f;
  float m_[2] = {-1e30f, -1e30f}, l_[2] = {0.f, 0.f};

  for (int kt = 0; kt < 16; ++kt) {
    if (kt < 15) {
      const _Float16* nsg = sg + (kt + 1) * sstep;
#pragma unroll
      for (int c = 0; c < 4; c++) pf[c] = *(const u32x4*)(nsg + c * 8);
    }
    __syncthreads();
    const _Float16* Ks = &smem[kt & 1][0][0];
    const _Float16* Vs = &smem[kt & 1][1][0];

    // S^T = K Q^T : 2 m-frags (64 keys) x 2 n-frags (64 q)
    f32x16 sf[2][2];
#pragma unroll
    for (int M = 0; M < 2; M++)
#pragma unroll
      for (int N = 0; N < 2; N++)
#pragma unroll
        for (int r = 0; r < 16; r++) sf[M][N][r] = 0.f;
#pragma unroll
    for (int s = 0; s < 4; s++) {
      half8 ka0 = *(const half8*)&Ks[l31 * 72 + s * 16 + h * 8];
      half8 ka1 = *(const half8*)&Ks[(32 + l31) * 72 + s * 16 + h * 8];
#pragma unroll
      for (int N = 0; N < 2; N++) {
        sf[0][N] = __builtin_amdgcn_mfma_f32_32x32x16_f16(ka0, qb[N][s], sf[0][N], 0, 0, 0);
        sf[1][N] = __builtin_amdgcn_mfma_f32_32x32x16_f16(ka1, qb[N][s], sf[1][N], 0, 0, 0);
      }
    }

    // online softmax; stats are per q = per lane (col of S^T)
    float alpha[2], c1[2], tsum[2];
#pragma unroll
    for (int N = 0; N < 2; N++) {
      float tmax = -1e30f;
#pragma unroll
      for (int r = 0; r < 16; r++)
        tmax = fmaxf(tmax, fmaxf(sf[0][N][r], sf[1][N][r]));
      tmax = fmaxf(tmax, __shfl_xor(tmax, 32, 64));
      float mnew = fmaxf(m_[N], tmax);
      alpha[N] = __builtin_amdgcn_exp2f((m_[N] - mnew) * LOG2E);
      m_[N] = mnew;
      c1[N] = mnew * LOG2E;
      tsum[N] = 0.f;
    }

    // exp -> P^T, pack fp16 pairs into dwords (kept in registers)
    int pdw[2][2][8];
#pragma unroll
    for (int M = 0; M < 2; M++)
#pragma unroll
      for (int N = 0; N < 2; N++) {
#pragma unroll
        for (int r = 0; r < 16; r++) {
          float p = __builtin_amdgcn_exp2f(sf[M][N][r] * LOG2E - c1[N]);
          sf[M][N][r] = p;
          tsum[N] += p;
        }
#pragma unroll
        for (int u = 0; u < 8; u++)
          pdw[M][N][u] = pack_rtz(sf[M][N][2 * u], sf[M][N][2 * u + 1]);
      }
#pragma unroll
    for (int N = 0; N < 2; N++) {
      tsum[N] += __shfl_xor(tsum[N], 32, 64);
      l_[N] = l_[N] * alpha[N] + tsum[N];
    }
#pragma unroll
    for (int D = 0; D < 2; D++)
#pragma unroll
      for (int N = 0; N < 2; N++)
#pragma unroll
        for (int r = 0; r < 16; r++) of[D][N][r] *= alpha[N];

    // O^T += V^T P^T ; P^T B-frags assembled from pdw via lane^32 half-swap
#pragma unroll
    for (int t = 0; t < 4; ++t) {
      const int M = t >> 1, s2 = (t & 1) * 4;
      half8 va0 = *(const half8*)&Vs[l31 * 72 + t * 16 + h * 8];
      half8 va1 = *(const half8*)&Vs[(32 + l31) * 72 + t * 16 + h * 8];
#pragma unroll
      for (int N = 0; N < 2; N++) {
        int a0 = pdw[M][N][s2 + 0], a1 = pdw[M][N][s2 + 1];
        int a2 = pdw[M][N][s2 + 2], a3 = pdw[M][N][s2 + 3];
        int e0 = h ? a0 : a2, e1 = h ? a1 : a3;
        int r0 = __shfl_xor(e0, 32, 64), r1 = __shfl_xor(e1, 32, 64);
        union { u32x4 u; half8 hv; } bb;
        bb.u[0] = h ? r0 : a0; bb.u[1] = h ? r1 : a1;
        bb.u[2] = h ? a2 : r0; bb.u[3] = h ? a3 : r1;
        of[0][N] = __builtin_amdgcn_mfma_f32_32x32x16_f16(va0, bb.hv, of[0][N], 0, 0, 0);
        of[1][N] = __builtin_amdgcn_mfma_f32_32x32x16_f16(va1, bb.hv, of[1][N], 0, 0, 0);
      }
    }

    if (kt < 15) {
      _Float16* dst = &smem[(kt + 1) & 1][0][0] + soff;
#pragma unroll
      for (int c = 0; c < 4; c++) *(u32x4*)(dst + c * 8) = pf[c];
    }
  }

  // epilogue: normalize, transpose O^T -> O through LDS, coalesced store
  __syncthreads();                       // all waves done with staging buffers
  float inv[2] = {1.0f / l_[0], 1.0f / l_[1]};
  int* OW = (int*)OLds;
#pragma unroll
  for (int N = 0; N < 2; N++) {
    const int q_local = w * 64 + N * 32 + l31;
#pragma unroll
    for (int D = 0; D < 2; D++)
#pragma unroll
      for (int u = 0; u < 8; u++) {
        int v = pack_rtz(of[D][N][2 * u] * inv[N], of[D][N][2 * u + 1] * inv[N]);
        int dwi = 16 * D + 4 * (u >> 1) + (u & 1) + 2 * h;
        OW[q_local * 36 + dwi] = v;
      }
  }
  __syncthreads();
#pragma unroll
  for (int p = 0; p < 8; p++) {
    int q = p * 32 + (tid >> 3), c = tid & 7;
    *(u32x4*)(Oh + (size_t)(b * SEQ + q0 + q) * DM + hh * HD + c * 8) =
        *(const u32x4*)&OLds[q * 72 + c * 8];
  }
}

// ---------------------------------------------------------------------------
// GEMM2: out = Oh[16384x768] @ wprojT^T + bias  (fp32 direct stores)
// ---------------------------------------------------------------------------
__launch_bounds__(256)
__global__ void gemm_proj_kernel(const _Float16* __restrict__ A,
                                 const _Float16* __restrict__ Bt,
                                 const float* __restrict__ bias,
                                 float* __restrict__ out) {
  __shared__ _Float16 As[128 * 32];
  __shared__ _Float16 Bs[128 * 32];
  const int tid  = threadIdx.x;
  const int m0   = blockIdx.y * 128;
  const int n0   = blockIdx.x * 128;
  const int w    = tid >> 6, lane = tid & 63;
  const int quad = lane >> 4, l15 = lane & 15;
  const int wr   = w >> 1, wc = w & 1;

  f32x4 acc[4][4] = {};

  const int e  = tid * 8;
  const int rA = e >> 5;
  const int kA = e & 31;
  const _Float16* ga = A  + (size_t)(m0 + rA) * 768 + kA;
  const _Float16* gb = Bt + (size_t)(n0 + rA) * 768 + kA;

  for (int kt = 0; kt < 24; ++kt) {
    __syncthreads();
    const int k0 = kt * 32;
    async16(ga + k0,            &As[e]);
    async16(ga + k0 + 64 * 768, &As[e + 2048]);
    async16(gb + k0,            &Bs[e]);
    async16(gb + k0 + 64 * 768, &Bs[e + 2048]);
    __syncthreads();

    half8 af[4], bf[4];
#pragma unroll
    for (int mi = 0; mi < 4; mi++)
      af[mi] = *(const half8*)&As[(wr * 64 + mi * 16 + l15) * 32 + quad * 8];
#pragma unroll
    for (int ni = 0; ni < 4; ni++)
      bf[ni] = *(const half8*)&Bs[(wc * 64 + ni * 16 + l15) * 32 + quad * 8];
#pragma unroll
    for (int mi = 0; mi < 4; mi++)
#pragma unroll
      for (int ni = 0; ni < 4; ni++)
        acc[mi][ni] = __builtin_amdgcn_mfma_f32_16x16x32_f16(
            af[mi], bf[ni], acc[mi][ni], 0, 0, 0);
  }

  float bcol[4];
#pragma unroll
  for (int ni = 0; ni < 4; ni++)
    bcol[ni] = bias[n0 + wc * 64 + ni * 16 + l15];
#pragma unroll
  for (int mi = 0; mi < 4; mi++)
#pragma unroll
    for (int ni = 0; ni < 4; ni++) {
      int col = n0 + wc * 64 + ni * 16 + l15;
      int row = m0 + wr * 64 + mi * 16 + quad * 4;
#pragma unroll
      for (int r = 0; r < 4; r++)
        out[(size_t)(row + r) * 768 + col] = acc[mi][ni][r] + bcol[ni];
    }
}

// ---------------------------------------------------------------------------
// launch
// ---------------------------------------------------------------------------
extern "C" void kernel_launch(void* const* d_in, const int* in_sizes, int n_in,
                              void* d_out, int out_size, void* d_ws, size_t ws_size,
                              hipStream_t stream) {
  const float* x      = (const float*)d_in[0];
  const float* w_qkv  = (const float*)d_in[1];
  const float* b_qkv  = (const float*)d_in[2];
  const float* w_proj = (const float*)d_in[3];
  const float* b_proj = (const float*)d_in[4];
  float* out = (float*)d_out;

  char* ws = (char*)d_ws;
  _Float16* xh     = (_Float16*)(ws);
  _Float16* wqkvT  = (_Float16*)(ws + 25165824);
  _Float16* wprojT = (_Float16*)(ws + 28704768);
  _Float16* Qp     = (_Float16*)(ws + 29884416);
  _Float16* Kp     = (_Float16*)(ws + 55050240);
  _Float16* VTp    = (_Float16*)(ws + 80216064);
  _Float16* Ohp    = (_Float16*)(ws + 105381888);
  // total: 130547712 B (~125 MB)

  cvt_x_kernel<<<dim3(3145728 / 256), 256, 0, stream>>>(x, xh, 3145728);
  cvt_wt_kernel<<<dim3(24, 72), 256, 0, stream>>>(w_qkv, wqkvT, 768, 2304);
  cvt_wt_kernel<<<dim3(24, 24), 256, 0, stream>>>(w_proj, wprojT, 768, 768);
  gemm_qkv_kernel<<<dim3(18, 128), 256, 0, stream>>>(xh, wqkvT, b_qkv, Qp, Kp, VTp);
  attn_kernel<<<dim3(768), 256, 0, stream>>>(Qp, Kp, VTp, Ohp);
  gemm_proj_kernel<<<dim3(6, 128), 256, 0, stream>>>(Ohp, wprojT, b_proj, out);
}

// Round 5
// 310.565 us; speedup vs baseline: 1.4141x; 1.0344x over previous
//
#include <hip/hip_runtime.h>

// ---------------------------------------------------------------------------
// Fused MHA block on gfx950, fp16 MFMA pipeline.
//   qkv GEMM (16384x2304x768) -> per-head flash attention (192 x 1024x1024x64)
//   -> proj GEMM (16384x768x768)
// GEMMs: v_mfma_f32_16x16x32_f16, 128x128 tiles, global_load_lds staging,
//        XCD-swizzled grid (column tiles of one m0 share an XCD's L2),
//        two-pass epilogue (Cs = 64 rows) for 4 blocks/CU occupancy.
// Attention: v_mfma_f32_32x32x16_f16 in TRANSPOSED orientation
//        (S^T = K Q^T, O^T = V^T P^T) so P stays in registers.
// ---------------------------------------------------------------------------

typedef _Float16 half8 __attribute__((ext_vector_type(8)));
typedef _Float16 half4 __attribute__((ext_vector_type(4)));
typedef __fp16   fp16x2 __attribute__((ext_vector_type(2)));
typedef float    f32x4  __attribute__((ext_vector_type(4)));
typedef float    f32x16 __attribute__((ext_vector_type(16)));
typedef unsigned int u32x4 __attribute__((ext_vector_type(4)));

#define DI __device__ __forceinline__

constexpr int   BATCH  = 16;
constexpr int   SEQ    = 1024;
constexpr int   DM     = 768;
constexpr int   NH     = 12;
constexpr int   HD     = 64;
constexpr float SCALE  = 0.125f;          // 1/sqrt(64), folded into Q epilogue
constexpr float LOG2E  = 1.4426950408889634f;

// async global->LDS, 16B per lane (dest must be wave-uniform base + lane*16)
DI void async16(const _Float16* g, _Float16* l) {
  __builtin_amdgcn_global_load_lds(
      (const __attribute__((address_space(1))) void*)g,
      (__attribute__((address_space(3))) void*)l, 16, 0, 0);
}

DI void copy16(_Float16* dst, const _Float16* src) {
  *(u32x4*)dst = *(const u32x4*)src;
}

DI int pack_rtz(float a, float b) {
  union { fp16x2 h; int i; } u;
  u.h = __builtin_amdgcn_cvt_pkrtz(a, b);
  return u.i;
}

// ---------------------------------------------------------------------------
// converts
// ---------------------------------------------------------------------------
__global__ void cvt_x_kernel(const float* __restrict__ x,
                             _Float16* __restrict__ xh, int n4) {
  int i = blockIdx.x * 256 + threadIdx.x;
  if (i >= n4) return;
  float4 v = ((const float4*)x)[i];
  half4 h;
  h[0] = (_Float16)v.x; h[1] = (_Float16)v.y;
  h[2] = (_Float16)v.z; h[3] = (_Float16)v.w;
  *(half4*)(xh + (size_t)i * 4) = h;
}

// both weight transposes in one launch: wt[n*K+k] = w[k*N+n]
__global__ void cvt_wt2_kernel(const float* __restrict__ wq,
                               _Float16* __restrict__ wqT,
                               const float* __restrict__ wp,
                               _Float16* __restrict__ wpT) {
  __shared__ float tile[32][33];
  const int by = blockIdx.y;
  const float* w; _Float16* wt; int N, nb;
  if (by < 72) { w = wq; wt = wqT; N = 2304; nb = by * 32; }
  else         { w = wp; wt = wpT; N = 768;  nb = (by - 72) * 32; }
  const int K = 768;
  int kb = blockIdx.x * 32;
  int tx = threadIdx.x & 31, ty = threadIdx.x >> 5;   // ty 0..7
#pragma unroll
  for (int i = 0; i < 32; i += 8)
    tile[ty + i][tx] = w[(size_t)(kb + ty + i) * N + nb + tx];
  __syncthreads();
#pragma unroll
  for (int i = 0; i < 32; i += 8)
    wt[(size_t)(nb + ty + i) * K + kb + tx] = (_Float16)tile[tx][ty + i];
}

// ---------------------------------------------------------------------------
// GEMM1: qkv = xh[16384x768] @ wqkvT^T + bias, scatter epilogue into
//   Q[bh][n][d] (prescaled by 0.125), K[bh][n][d], VT[bh][d][n]  (fp16)
// ---------------------------------------------------------------------------
__launch_bounds__(256, 4)
__global__ void gemm_qkv_kernel(const _Float16* __restrict__ A,
                                const _Float16* __restrict__ Bt,
                                const float* __restrict__ bias,
                                _Float16* __restrict__ Qo,
                                _Float16* __restrict__ Ko,
                                _Float16* __restrict__ VTo) {
  __shared__ _Float16 As[128 * 32];
  __shared__ _Float16 Bs[128 * 32];
  __shared__ _Float16 Cs[64 * 136];    // 64-row epilogue buffer (two passes)
  const int tid  = threadIdx.x;
  // XCD swizzle: all 18 column tiles of one m0 land on one XCD (lin&7)
  const int lin  = blockIdx.x;
  const int xcd  = lin & 7, j = lin >> 3;
  const int ct   = j % 18;             // 0..17 col tiles
  const int m0   = ((j / 18) * 8 + xcd) * 128;
  const int n0   = ct * 128;
  const int w    = tid >> 6, lane = tid & 63;
  const int quad = lane >> 4, l15 = lane & 15;
  const int wr   = w >> 1, wc = w & 1;

  f32x4 acc[4][4] = {};

  const int e  = tid * 8;
  const int rA = e >> 5;
  const int kA = e & 31;
  const _Float16* ga = A  + (size_t)(m0 + rA) * 768 + kA;
  const _Float16* gb = Bt + (size_t)(n0 + rA) * 768 + kA;

  for (int kt = 0; kt < 24; ++kt) {
    __syncthreads();
    const int k0 = kt * 32;
    async16(ga + k0,            &As[e]);
    async16(ga + k0 + 64 * 768, &As[e + 2048]);
    async16(gb + k0,            &Bs[e]);
    async16(gb + k0 + 64 * 768, &Bs[e + 2048]);
    __syncthreads();

    half8 af[4], bf[4];
#pragma unroll
    for (int mi = 0; mi < 4; mi++)
      af[mi] = *(const half8*)&As[(wr * 64 + mi * 16 + l15) * 32 + quad * 8];
#pragma unroll
    for (int ni = 0; ni < 4; ni++)
      bf[ni] = *(const half8*)&Bs[(wc * 64 + ni * 16 + l15) * 32 + quad * 8];
#pragma unroll
    for (int mi = 0; mi < 4; mi++)
#pragma unroll
      for (int ni = 0; ni < 4; ni++)
        acc[mi][ni] = __builtin_amdgcn_mfma_f32_16x16x32_f16(
            af[mi], bf[ni], acc[mi][ni], 0, 0, 0);
  }

  const float oscale = (ct < 6) ? SCALE : 1.0f;
  float bcol[4];
#pragma unroll
  for (int ni = 0; ni < 4; ni++)
    bcol[ni] = bias[n0 + wc * 64 + ni * 16 + l15];

  const int b     = m0 >> 10;
  const int nrow0 = m0 & 1023;
  const int sec   = ct / 6;            // 0=Q 1=K 2=V
  const int h0    = (ct % 6) * 2;

  // two passes of 64 rows each: waves with wr==p write, everyone scatters
#pragma unroll
  for (int p = 0; p < 2; ++p) {
    if (p) __syncthreads();            // pass-0 reads done before overwrite
    if (wr == p) {
#pragma unroll
      for (int mi = 0; mi < 4; mi++)
#pragma unroll
        for (int ni = 0; ni < 4; ni++) {
          int col = wc * 64 + ni * 16 + l15;
          int row = mi * 16 + quad * 4;
#pragma unroll
          for (int r = 0; r < 4; r++)
            Cs[(row + r) * 136 + col] =
                (_Float16)((acc[mi][ni][r] + bcol[ni]) * oscale);
        }
    }
    __syncthreads();

    if (sec < 2) {
      _Float16* dst = (sec == 0) ? Qo : Ko;
      int row = tid >> 2, seg = tid & 3;
      int hl = seg >> 1, off32 = (seg & 1) * 32;
      _Float16* g = dst +
          ((size_t)((b * NH + h0 + hl) * SEQ + nrow0 + p * 64 + row)) * HD + off32;
      const _Float16* s = &Cs[row * 136 + hl * 64 + off32];
      copy16(g, s);
      copy16(g + 8, s + 8);
      copy16(g + 16, s + 16);
      copy16(g + 24, s + 24);
    } else {
      int c = tid & 127, half = tid >> 7;   // col, row half (32 rows each)
      int hl = c >> 6, d = c & 63;
      _Float16 tmp[32];
#pragma unroll
      for (int jj = 0; jj < 32; jj++) tmp[jj] = Cs[(half * 32 + jj) * 136 + c];
      _Float16* g = VTo + ((size_t)((b * NH + h0 + hl) * HD + d)) * SEQ
                        + nrow0 + p * 64 + half * 32;
#pragma unroll
      for (int jj = 0; jj < 4; jj++)
        copy16(g + jj * 8, (const _Float16*)&tmp[jj * 8]);
    }
  }
}

// ---------------------------------------------------------------------------
// Flash attention, transposed: one wg = (bh, 256-q tile), 4 waves x 64 q.
// S^T = K Q^T (32x32x16 MFMA), P^T kept in registers via half-swap shuffles,
// O^T = V^T P^T.  K-tile 64, double-buffered LDS staging.
// ---------------------------------------------------------------------------
__launch_bounds__(256, 2)
__global__ void attn_kernel(const _Float16* __restrict__ Q,
                            const _Float16* __restrict__ K,
                            const _Float16* __restrict__ VT,
                            _Float16* __restrict__ Oh) {
  __shared__ _Float16 smem[2][2][64 * 72];   // [buf][K/V][64 rows][72]
  _Float16* OLds = &smem[0][0][0];           // aliased epilogue staging (36864B)

  const int tid = threadIdx.x;
  const int i   = blockIdx.x;
  const int bh  = (i & 7) * 24 + ((i >> 3) >> 2);   // XCD swizzle: 4 q-blocks
  const int q0  = ((i >> 3) & 3) * 256;             //  of one bh share an XCD
  const int b   = bh / NH, hh = bh - b * NH;
  const int w   = tid >> 6, lane = tid & 63;
  const int l31 = lane & 31, h = lane >> 5;

  const _Float16* Qg = Q  + (size_t)bh * SEQ * HD;
  const _Float16* Kg = K  + (size_t)bh * SEQ * HD;
  const _Float16* Vg = VT + (size_t)bh * HD * SEQ;

  // persistent Q B-frags: qb[N][s] ; B[k=d][n=q] read from Q[q][d] row-major
  half8 qb[2][4];
#pragma unroll
  for (int N = 0; N < 2; N++) {
    const _Float16* qrow = Qg + (size_t)(q0 + w * 64 + N * 32 + l31) * HD + h * 8;
#pragma unroll
    for (int s = 0; s < 4; s++)
      qb[N][s] = *(const half8*)(qrow + s * 16);
  }

  // staging: threads 0-127 stage K tile, 128-255 stage V^T tile (64B each)
  const int  sr  = (tid & 127) >> 1;
  const int  sp  = tid & 1;
  const bool isK = tid < 128;
  const _Float16* sg = isK ? (Kg + sr * HD + sp * 32)
                           : (Vg + (size_t)sr * SEQ + sp * 32);
  const int sstep = isK ? 64 * HD : 64;
  const int soff  = (isK ? 0 : 64 * 72) + sr * 72 + sp * 32;

  u32x4 pf[4];
#pragma unroll
  for (int c = 0; c < 4; c++) pf[c] = *(const u32x4*)(sg + c * 8);
#pragma unroll
  for (int c = 0; c < 4; c++) *(u32x4*)(&smem[0][0][0] + soff + c * 8) = pf[c];

  f32x16 of[2][2];
#pragma unroll
  for (int D = 0; D < 2; D++)
#pragma unroll
    for (int N = 0; N < 2; N++)
#pragma unroll
      for (int r = 0; r < 16; r++) of[D][N][r] = 0.f;
  float m_[2] = {-1e30f, -1e30f}, l_[2] = {0.f, 0.f};

  for (int kt = 0; kt < 16; ++kt) {
    if (kt < 15) {
      const _Float16* nsg = sg + (kt + 1) * sstep;
#pragma unroll
      for (int c = 0; c < 4; c++) pf[c] = *(const u32x4*)(nsg + c * 8);
    }
    __syncthreads();
    const _Float16* Ks = &smem[kt & 1][0][0];
    const _Float16* Vs = &smem[kt & 1][1][0];

    // S^T = K Q^T : 2 m-frags (64 keys) x 2 n-frags (64 q)
    f32x16 sf[2][2];
#pragma unroll
    for (int M = 0; M < 2; M++)
#pragma unroll
      for (int N = 0; N < 2; N++)
#pragma unroll
        for (int r = 0; r < 16; r++) sf[M][N][r] = 0.f;
#pragma unroll
    for (int s = 0; s < 4; s++) {
      half8 ka0 = *(const half8*)&Ks[l31 * 72 + s * 16 + h * 8];
      half8 ka1 = *(const half8*)&Ks[(32 + l31) * 72 + s * 16 + h * 8];
#pragma unroll
      for (int N = 0; N < 2; N++) {
        sf[0][N] = __builtin_amdgcn_mfma_f32_32x32x16_f16(ka0, qb[N][s], sf[0][N], 0, 0, 0);
        sf[1][N] = __builtin_amdgcn_mfma_f32_32x32x16_f16(ka1, qb[N][s], sf[1][N], 0, 0, 0);
      }
    }

    // online softmax; stats are per q = per lane (col of S^T)
    float alpha[2], c1[2], tsum[2];
#pragma unroll
    for (int N = 0; N < 2; N++) {
      float tmax = -1e30f;
#pragma unroll
      for (int r = 0; r < 16; r++)
        tmax = fmaxf(tmax, fmaxf(sf[0][N][r], sf[1][N][r]));
      tmax = fmaxf(tmax, __shfl_xor(tmax, 32, 64));
      float mnew = fmaxf(m_[N], tmax);
      alpha[N] = __builtin_amdgcn_exp2f((m_[N] - mnew) * LOG2E);
      m_[N] = mnew;
      c1[N] = mnew * LOG2E;
      tsum[N] = 0.f;
    }

    // exp -> P^T, pack fp16 pairs into dwords (kept in registers)
    int pdw[2][2][8];
#pragma unroll
    for (int M = 0; M < 2; M++)
#pragma unroll
      for (int N = 0; N < 2; N++) {
#pragma unroll
        for (int r = 0; r < 16; r++) {
          float p = __builtin_amdgcn_exp2f(sf[M][N][r] * LOG2E - c1[N]);
          sf[M][N][r] = p;
          tsum[N] += p;
        }
#pragma unroll
        for (int u = 0; u < 8; u++)
          pdw[M][N][u] = pack_rtz(sf[M][N][2 * u], sf[M][N][2 * u + 1]);
      }
#pragma unroll
    for (int N = 0; N < 2; N++) {
      tsum[N] += __shfl_xor(tsum[N], 32, 64);
      l_[N] = l_[N] * alpha[N] + tsum[N];
    }
#pragma unroll
    for (int D = 0; D < 2; D++)
#pragma unroll
      for (int N = 0; N < 2; N++)
#pragma unroll
        for (int r = 0; r < 16; r++) of[D][N][r] *= alpha[N];

    // O^T += V^T P^T ; P^T B-frags assembled from pdw via lane^32 half-swap
#pragma unroll
    for (int t = 0; t < 4; ++t) {
      const int M = t >> 1, s2 = (t & 1) * 4;
      half8 va0 = *(const half8*)&Vs[l31 * 72 + t * 16 + h * 8];
      half8 va1 = *(const half8*)&Vs[(32 + l31) * 72 + t * 16 + h * 8];
#pragma unroll
      for (int N = 0; N < 2; N++) {
        int a0 = pdw[M][N][s2 + 0], a1 = pdw[M][N][s2 + 1];
        int a2 = pdw[M][N][s2 + 2], a3 = pdw[M][N][s2 + 3];
        int e0 = h ? a0 : a2, e1 = h ? a1 : a3;
        int r0 = __shfl_xor(e0, 32, 64), r1 = __shfl_xor(e1, 32, 64);
        union { u32x4 u; half8 hv; } bb;
        bb.u[0] = h ? r0 : a0; bb.u[1] = h ? r1 : a1;
        bb.u[2] = h ? a2 : r0; bb.u[3] = h ? a3 : r1;
        of[0][N] = __builtin_amdgcn_mfma_f32_32x32x16_f16(va0, bb.hv, of[0][N], 0, 0, 0);
        of[1][N] = __builtin_amdgcn_mfma_f32_32x32x16_f16(va1, bb.hv, of[1][N], 0, 0, 0);
      }
    }

    if (kt < 15) {
      _Float16* dst = &smem[(kt + 1) & 1][0][0] + soff;
#pragma unroll
      for (int c = 0; c < 4; c++) *(u32x4*)(dst + c * 8) = pf[c];
    }
  }

  // epilogue: normalize, transpose O^T -> O through LDS, coalesced store
  __syncthreads();                       // all waves done with staging buffers
  float inv[2] = {1.0f / l_[0], 1.0f / l_[1]};
  int* OW = (int*)OLds;
#pragma unroll
  for (int N = 0; N < 2; N++) {
    const int q_local = w * 64 + N * 32 + l31;
#pragma unroll
    for (int D = 0; D < 2; D++)
#pragma unroll
      for (int u = 0; u < 8; u++) {
        int v = pack_rtz(of[D][N][2 * u] * inv[N], of[D][N][2 * u + 1] * inv[N]);
        int dwi = 16 * D + 4 * (u >> 1) + (u & 1) + 2 * h;
        OW[q_local * 36 + dwi] = v;
      }
  }
  __syncthreads();
#pragma unroll
  for (int p = 0; p < 8; p++) {
    int q = p * 32 + (tid >> 3), c = tid & 7;
    *(u32x4*)(Oh + (size_t)(b * SEQ + q0 + q) * DM + hh * HD + c * 8) =
        *(const u32x4*)&OLds[q * 72 + c * 8];
  }
}

// ---------------------------------------------------------------------------
// GEMM2: out = Oh[16384x768] @ wprojT^T + bias  (fp32 direct stores)
// ---------------------------------------------------------------------------
__launch_bounds__(256, 4)
__global__ void gemm_proj_kernel(const _Float16* __restrict__ A,
                                 const _Float16* __restrict__ Bt,
                                 const float* __restrict__ bias,
                                 float* __restrict__ out) {
  __shared__ _Float16 As[128 * 32];
  __shared__ _Float16 Bs[128 * 32];
  const int tid  = threadIdx.x;
  // XCD swizzle: all 6 column tiles of one m0 on one XCD
  const int lin  = blockIdx.x;
  const int xcd  = lin & 7, j = lin >> 3;
  const int ct   = j % 6;
  const int m0   = ((j / 6) * 8 + xcd) * 128;
  const int n0   = ct * 128;
  const int w    = tid >> 6, lane = tid & 63;
  const int quad = lane >> 4, l15 = lane & 15;
  const int wr   = w >> 1, wc = w & 1;

  f32x4 acc[4][4] = {};

  const int e  = tid * 8;
  const int rA = e >> 5;
  const int kA = e & 31;
  const _Float16* ga = A  + (size_t)(m0 + rA) * 768 + kA;
  const _Float16* gb = Bt + (size_t)(n0 + rA) * 768 + kA;

  for (int kt = 0; kt < 24; ++kt) {
    __syncthreads();
    const int k0 = kt * 32;
    async16(ga + k0,            &As[e]);
    async16(ga + k0 + 64 * 768, &As[e + 2048]);
    async16(gb + k0,            &Bs[e]);
    async16(gb + k0 + 64 * 768, &Bs[e + 2048]);
    __syncthreads();

    half8 af[4], bf[4];
#pragma unroll
    for (int mi = 0; mi < 4; mi++)
      af[mi] = *(const half8*)&As[(wr * 64 + mi * 16 + l15) * 32 + quad * 8];
#pragma unroll
    for (int ni = 0; ni < 4; ni++)
      bf[ni] = *(const half8*)&Bs[(wc * 64 + ni * 16 + l15) * 32 + quad * 8];
#pragma unroll
    for (int mi = 0; mi < 4; mi++)
#pragma unroll
      for (int ni = 0; ni < 4; ni++)
        acc[mi][ni] = __builtin_amdgcn_mfma_f32_16x16x32_f16(
            af[mi], bf[ni], acc[mi][ni], 0, 0, 0);
  }

  float bcol[4];
#pragma unroll
  for (int ni = 0; ni < 4; ni++)
    bcol[ni] = bias[n0 + wc * 64 + ni * 16 + l15];
#pragma unroll
  for (int mi = 0; mi < 4; mi++)
#pragma unroll
    for (int ni = 0; ni < 4; ni++) {
      int col = n0 + wc * 64 + ni * 16 + l15;
      int row = m0 + wr * 64 + mi * 16 + quad * 4;
#pragma unroll
      for (int r = 0; r < 4; r++)
        out[(size_t)(row + r) * 768 + col] = acc[mi][ni][r] + bcol[ni];
    }
}

// ---------------------------------------------------------------------------
// launch
// ---------------------------------------------------------------------------
extern "C" void kernel_launch(void* const* d_in, const int* in_sizes, int n_in,
                              void* d_out, int out_size, void* d_ws, size_t ws_size,
                              hipStream_t stream) {
  const float* x      = (const float*)d_in[0];
  const float* w_qkv  = (const float*)d_in[1];
  const float* b_qkv  = (const float*)d_in[2];
  const float* w_proj = (const float*)d_in[3];
  const float* b_proj = (const float*)d_in[4];
  float* out = (float*)d_out;

  char* ws = (char*)d_ws;
  _Float16* xh     = (_Float16*)(ws);
  _Float16* wqkvT  = (_Float16*)(ws + 25165824);
  _Float16* wprojT = (_Float16*)(ws + 28704768);
  _Float16* Qp     = (_Float16*)(ws + 29884416);
  _Float16* Kp     = (_Float16*)(ws + 55050240);
  _Float16* VTp    = (_Float16*)(ws + 80216064);
  _Float16* Ohp    = (_Float16*)(ws + 105381888);
  // total: 130547712 B (~125 MB)

  cvt_x_kernel<<<dim3(3145728 / 256), 256, 0, stream>>>(x, xh, 3145728);
  cvt_wt2_kernel<<<dim3(24, 96), 256, 0, stream>>>(w_qkv, wqkvT, w_proj, wprojT);
  gemm_qkv_kernel<<<dim3(2304), 256, 0, stream>>>(xh, wqkvT, b_qkv, Qp, Kp, VTp);
  attn_kernel<<<dim3(768), 256, 0, stream>>>(Qp, Kp, VTp, Ohp);
  gemm_proj_kernel<<<dim3(768), 256, 0, stream>>>(Ohp, wprojT, b_proj, out);
}

// Round 6
// 306.475 us; speedup vs baseline: 1.4329x; 1.0133x over previous
//
#include <hip/hip_runtime.h>

// ---------------------------------------------------------------------------
// Fused MHA block on gfx950, fp16 MFMA pipeline.
//   qkv GEMM (16384x2304x768) -> per-head flash attention (192 x 1024x1024x64)
//   -> proj GEMM (16384x768x768)
// GEMMs: v_mfma_f32_16x16x32_f16, 128x128 tiles, register-prefetch
//        double-buffered LDS pipeline (1 barrier/iter, no vmcnt(0) drain),
//        stride-40 padded LDS (2-way bank aliasing = free),
//        XCD-swizzled grid (column tiles of one m0 share an XCD's L2).
// Attention: v_mfma_f32_32x32x16_f16 in TRANSPOSED orientation
//        (S^T = K Q^T, O^T = V^T P^T) so P stays in registers.
// ---------------------------------------------------------------------------

typedef _Float16 half8 __attribute__((ext_vector_type(8)));
typedef _Float16 half4 __attribute__((ext_vector_type(4)));
typedef __fp16   fp16x2 __attribute__((ext_vector_type(2)));
typedef float    f32x4  __attribute__((ext_vector_type(4)));
typedef float    f32x16 __attribute__((ext_vector_type(16)));
typedef unsigned int u32x4 __attribute__((ext_vector_type(4)));

#define DI __device__ __forceinline__

constexpr int   BATCH  = 16;
constexpr int   SEQ    = 1024;
constexpr int   DM     = 768;
constexpr int   NH     = 12;
constexpr int   HD     = 64;
constexpr float SCALE  = 0.125f;          // 1/sqrt(64), folded into Q epilogue
constexpr float LOG2E  = 1.4426950408889634f;

DI void copy16(_Float16* dst, const _Float16* src) {
  *(u32x4*)dst = *(const u32x4*)src;
}

DI int pack_rtz(float a, float b) {
  union { fp16x2 h; int i; } u;
  u.h = __builtin_amdgcn_cvt_pkrtz(a, b);
  return u.i;
}

// ---------------------------------------------------------------------------
// converts
// ---------------------------------------------------------------------------
__global__ void cvt_x_kernel(const float* __restrict__ x,
                             _Float16* __restrict__ xh, int n4) {
  int i = blockIdx.x * 256 + threadIdx.x;
  if (i >= n4) return;
  float4 v = ((const float4*)x)[i];
  half4 h;
  h[0] = (_Float16)v.x; h[1] = (_Float16)v.y;
  h[2] = (_Float16)v.z; h[3] = (_Float16)v.w;
  *(half4*)(xh + (size_t)i * 4) = h;
}

// both weight transposes in one launch: wt[n*K+k] = w[k*N+n]
__global__ void cvt_wt2_kernel(const float* __restrict__ wq,
                               _Float16* __restrict__ wqT,
                               const float* __restrict__ wp,
                               _Float16* __restrict__ wpT) {
  __shared__ float tile[32][33];
  const int by = blockIdx.y;
  const float* w; _Float16* wt; int N, nb;
  if (by < 72) { w = wq; wt = wqT; N = 2304; nb = by * 32; }
  else         { w = wp; wt = wpT; N = 768;  nb = (by - 72) * 32; }
  const int K = 768;
  int kb = blockIdx.x * 32;
  int tx = threadIdx.x & 31, ty = threadIdx.x >> 5;   // ty 0..7
#pragma unroll
  for (int i = 0; i < 32; i += 8)
    tile[ty + i][tx] = w[(size_t)(kb + ty + i) * N + nb + tx];
  __syncthreads();
#pragma unroll
  for (int i = 0; i < 32; i += 8)
    wt[(size_t)(nb + ty + i) * K + kb + tx] = (_Float16)tile[tx][ty + i];
}

// ---------------------------------------------------------------------------
// GEMM1: qkv = xh[16384x768] @ wqkvT^T + bias, scatter epilogue into
//   Q[bh][n][d] (prescaled by 0.125), K[bh][n][d], VT[bh][d][n]  (fp16)
// ---------------------------------------------------------------------------
__launch_bounds__(256, 3)
__global__ void gemm_qkv_kernel(const _Float16* __restrict__ A,
                                const _Float16* __restrict__ Bt,
                                const float* __restrict__ bias,
                                _Float16* __restrict__ Qo,
                                _Float16* __restrict__ Ko,
                                _Float16* __restrict__ VTo) {
  // 2 bufs x (As 128x40 + Bs 128x40) halves = 40960 B
  __shared__ _Float16 sh[20480];
  _Float16* Cs = sh;                 // epilogue alias (64*136 = 8704 halves)
  const int tid  = threadIdx.x;
  // XCD swizzle: all 18 column tiles of one m0 land on one XCD (lin&7)
  const int lin  = blockIdx.x;
  const int xcd  = lin & 7, j = lin >> 3;
  const int ct   = j % 18;             // 0..17 col tiles
  const int m0   = ((j / 18) * 8 + xcd) * 128;
  const int n0   = ct * 128;
  const int w    = tid >> 6, lane = tid & 63;
  const int quad = lane >> 4, l15 = lane & 15;
  const int wr   = w >> 1, wc = w & 1;

  f32x4 acc[4][4] = {};

  const int e  = tid * 8;
  const int rA = e >> 5;             // row 0..63 (also stages row+64)
  const int g8 = e & 31;             // group offset in halves: 0,8,16,24
  const _Float16* ga = A  + (size_t)(m0 + rA) * 768 + g8;
  const _Float16* gb = Bt + (size_t)(n0 + rA) * 768 + g8;
  const int so = rA * 40 + g8;       // padded stride 40 halves (80 B)

  u32x4 pA0 = *(const u32x4*)ga;
  u32x4 pA1 = *(const u32x4*)(ga + 64 * 768);
  u32x4 pB0 = *(const u32x4*)gb;
  u32x4 pB1 = *(const u32x4*)(gb + 64 * 768);
  {
    _Float16* As = sh; _Float16* Bs = sh + 5120;
    *(u32x4*)(As + so) = pA0; *(u32x4*)(As + so + 64 * 40) = pA1;
    *(u32x4*)(Bs + so) = pB0; *(u32x4*)(Bs + so + 64 * 40) = pB1;
  }

  for (int kt = 0; kt < 24; ++kt) {
    __syncthreads();
    if (kt < 23) {                   // prefetch next tile into registers
      const int k0 = (kt + 1) * 32;
      pA0 = *(const u32x4*)(ga + k0);
      pA1 = *(const u32x4*)(ga + k0 + 64 * 768);
      pB0 = *(const u32x4*)(gb + k0);
      pB1 = *(const u32x4*)(gb + k0 + 64 * 768);
    }
    const _Float16* As = sh + (kt & 1) * 10240;
    const _Float16* Bs = As + 5120;

    half8 af[4], bf[4];
#pragma unroll
    for (int mi = 0; mi < 4; mi++)
      af[mi] = *(const half8*)&As[(wr * 64 + mi * 16 + l15) * 40 + quad * 8];
#pragma unroll
    for (int ni = 0; ni < 4; ni++)
      bf[ni] = *(const half8*)&Bs[(wc * 64 + ni * 16 + l15) * 40 + quad * 8];
#pragma unroll
    for (int mi = 0; mi < 4; mi++)
#pragma unroll
      for (int ni = 0; ni < 4; ni++)
        acc[mi][ni] = __builtin_amdgcn_mfma_f32_16x16x32_f16(
            af[mi], bf[ni], acc[mi][ni], 0, 0, 0);

    if (kt < 23) {                   // stage prefetched tile into other buf
      _Float16* Asn = sh + ((kt + 1) & 1) * 10240;
      _Float16* Bsn = Asn + 5120;
      *(u32x4*)(Asn + so) = pA0; *(u32x4*)(Asn + so + 64 * 40) = pA1;
      *(u32x4*)(Bsn + so) = pB0; *(u32x4*)(Bsn + so + 64 * 40) = pB1;
    }
  }
  __syncthreads();

  const float oscale = (ct < 6) ? SCALE : 1.0f;
  float bcol[4];
#pragma unroll
  for (int ni = 0; ni < 4; ni++)
    bcol[ni] = bias[n0 + wc * 64 + ni * 16 + l15];

  const int b     = m0 >> 10;
  const int nrow0 = m0 & 1023;
  const int sec   = ct / 6;            // 0=Q 1=K 2=V
  const int h0    = (ct % 6) * 2;

  // two passes of 64 rows each through Cs
#pragma unroll
  for (int p = 0; p < 2; ++p) {
    if (p) __syncthreads();            // pass-0 reads done before overwrite
    if (wr == p) {
#pragma unroll
      for (int mi = 0; mi < 4; mi++)
#pragma unroll
        for (int ni = 0; ni < 4; ni++) {
          int col = wc * 64 + ni * 16 + l15;
          int row = mi * 16 + quad * 4;
#pragma unroll
          for (int r = 0; r < 4; r++)
            Cs[(row + r) * 136 + col] =
                (_Float16)((acc[mi][ni][r] + bcol[ni]) * oscale);
        }
    }
    __syncthreads();

    if (sec < 2) {
      _Float16* dst = (sec == 0) ? Qo : Ko;
      int row = tid >> 2, seg = tid & 3;
      int hl = seg >> 1, off32 = (seg & 1) * 32;
      _Float16* g = dst +
          ((size_t)((b * NH + h0 + hl) * SEQ + nrow0 + p * 64 + row)) * HD + off32;
      const _Float16* s = &Cs[row * 136 + hl * 64 + off32];
      copy16(g, s);
      copy16(g + 8, s + 8);
      copy16(g + 16, s + 16);
      copy16(g + 24, s + 24);
    } else {
      int c = tid & 127, half = tid >> 7;   // col, row half (32 rows each)
      int hl = c >> 6, d = c & 63;
      _Float16 tmp[32];
#pragma unroll
      for (int jj = 0; jj < 32; jj++) tmp[jj] = Cs[(half * 32 + jj) * 136 + c];
      _Float16* g = VTo + ((size_t)((b * NH + h0 + hl) * HD + d)) * SEQ
                        + nrow0 + p * 64 + half * 32;
#pragma unroll
      for (int jj = 0; jj < 4; jj++)
        copy16(g + jj * 8, (const _Float16*)&tmp[jj * 8]);
    }
  }
}

// ---------------------------------------------------------------------------
// Flash attention, transposed: one wg = (bh, 256-q tile), 4 waves x 64 q.
// S^T = K Q^T (32x32x16 MFMA), P^T kept in registers via half-swap shuffles,
// O^T = V^T P^T.  K-tile 64, double-buffered LDS staging.
// ---------------------------------------------------------------------------
__launch_bounds__(256, 2)
__global__ void attn_kernel(const _Float16* __restrict__ Q,
                            const _Float16* __restrict__ K,
                            const _Float16* __restrict__ VT,
                            _Float16* __restrict__ Oh) {
  __shared__ _Float16 smem[2][2][64 * 72];   // [buf][K/V][64 rows][72]
  _Float16* OLds = &smem[0][0][0];           // aliased epilogue staging (36864B)

  const int tid = threadIdx.x;
  const int i   = blockIdx.x;
  const int bh  = (i & 7) * 24 + ((i >> 3) >> 2);   // XCD swizzle: 4 q-blocks
  const int q0  = ((i >> 3) & 3) * 256;             //  of one bh share an XCD
  const int b   = bh / NH, hh = bh - b * NH;
  const int w   = tid >> 6, lane = tid & 63;
  const int l31 = lane & 31, h = lane >> 5;

  const _Float16* Qg = Q  + (size_t)bh * SEQ * HD;
  const _Float16* Kg = K  + (size_t)bh * SEQ * HD;
  const _Float16* Vg = VT + (size_t)bh * HD * SEQ;

  // persistent Q B-frags: qb[N][s] ; B[k=d][n=q] read from Q[q][d] row-major
  half8 qb[2][4];
#pragma unroll
  for (int N = 0; N < 2; N++) {
    const _Float16* qrow = Qg + (size_t)(q0 + w * 64 + N * 32 + l31) * HD + h * 8;
#pragma unroll
    for (int s = 0; s < 4; s++)
      qb[N][s] = *(const half8*)(qrow + s * 16);
  }

  // staging: threads 0-127 stage K tile, 128-255 stage V^T tile (64B each)
  const int  sr  = (tid & 127) >> 1;
  const int  sp  = tid & 1;
  const bool isK = tid < 128;
  const _Float16* sg = isK ? (Kg + sr * HD + sp * 32)
                           : (Vg + (size_t)sr * SEQ + sp * 32);
  const int sstep = isK ? 64 * HD : 64;
  const int soff  = (isK ? 0 : 64 * 72) + sr * 72 + sp * 32;

  u32x4 pf[4];
#pragma unroll
  for (int c = 0; c < 4; c++) pf[c] = *(const u32x4*)(sg + c * 8);
#pragma unroll
  for (int c = 0; c < 4; c++) *(u32x4*)(&smem[0][0][0] + soff + c * 8) = pf[c];

  f32x16 of[2][2];
#pragma unroll
  for (int D = 0; D < 2; D++)
#pragma unroll
    for (int N = 0; N < 2; N++)
#pragma unroll
      for (int r = 0; r < 16; r++) of[D][N][r] = 0.f;
  float m_[2] = {-1e30f, -1e30f}, l_[2] = {0.f, 0.f};

  for (int kt = 0; kt < 16; ++kt) {
    if (kt < 15) {
      const _Float16* nsg = sg + (kt + 1) * sstep;
#pragma unroll
      for (int c = 0; c < 4; c++) pf[c] = *(const u32x4*)(nsg + c * 8);
    }
    __syncthreads();
    const _Float16* Ks = &smem[kt & 1][0][0];
    const _Float16* Vs = &smem[kt & 1][1][0];

    // S^T = K Q^T : 2 m-frags (64 keys) x 2 n-frags (64 q)
    f32x16 sf[2][2];
#pragma unroll
    for (int M = 0; M < 2; M++)
#pragma unroll
      for (int N = 0; N < 2; N++)
#pragma unroll
        for (int r = 0; r < 16; r++) sf[M][N][r] = 0.f;
#pragma unroll
    for (int s = 0; s < 4; s++) {
      half8 ka0 = *(const half8*)&Ks[l31 * 72 + s * 16 + h * 8];
      half8 ka1 = *(const half8*)&Ks[(32 + l31) * 72 + s * 16 + h * 8];
#pragma unroll
      for (int N = 0; N < 2; N++) {
        sf[0][N] = __builtin_amdgcn_mfma_f32_32x32x16_f16(ka0, qb[N][s], sf[0][N], 0, 0, 0);
        sf[1][N] = __builtin_amdgcn_mfma_f32_32x32x16_f16(ka1, qb[N][s], sf[1][N], 0, 0, 0);
      }
    }

    // online softmax; stats are per q = per lane (col of S^T)
    float alpha[2], c1[2], tsum[2];
#pragma unroll
    for (int N = 0; N < 2; N++) {
      float tmax = -1e30f;
#pragma unroll
      for (int r = 0; r < 16; r++)
        tmax = fmaxf(tmax, fmaxf(sf[0][N][r], sf[1][N][r]));
      tmax = fmaxf(tmax, __shfl_xor(tmax, 32, 64));
      float mnew = fmaxf(m_[N], tmax);
      alpha[N] = __builtin_amdgcn_exp2f((m_[N] - mnew) * LOG2E);
      m_[N] = mnew;
      c1[N] = mnew * LOG2E;
      tsum[N] = 0.f;
    }

    // exp -> P^T, pack fp16 pairs into dwords (kept in registers)
    int pdw[2][2][8];
#pragma unroll
    for (int M = 0; M < 2; M++)
#pragma unroll
      for (int N = 0; N < 2; N++) {
#pragma unroll
        for (int r = 0; r < 16; r++) {
          float p = __builtin_amdgcn_exp2f(sf[M][N][r] * LOG2E - c1[N]);
          sf[M][N][r] = p;
          tsum[N] += p;
        }
#pragma unroll
        for (int u = 0; u < 8; u++)
          pdw[M][N][u] = pack_rtz(sf[M][N][2 * u], sf[M][N][2 * u + 1]);
      }
#pragma unroll
    for (int N = 0; N < 2; N++) {
      tsum[N] += __shfl_xor(tsum[N], 32, 64);
      l_[N] = l_[N] * alpha[N] + tsum[N];
    }
#pragma unroll
    for (int D = 0; D < 2; D++)
#pragma unroll
      for (int N = 0; N < 2; N++)
#pragma unroll
        for (int r = 0; r < 16; r++) of[D][N][r] *= alpha[N];

    // O^T += V^T P^T ; P^T B-frags assembled from pdw via lane^32 half-swap
#pragma unroll
    for (int t = 0; t < 4; ++t) {
      const int M = t >> 1, s2 = (t & 1) * 4;
      half8 va0 = *(const half8*)&Vs[l31 * 72 + t * 16 + h * 8];
      half8 va1 = *(const half8*)&Vs[(32 + l31) * 72 + t * 16 + h * 8];
#pragma unroll
      for (int N = 0; N < 2; N++) {
        int a0 = pdw[M][N][s2 + 0], a1 = pdw[M][N][s2 + 1];
        int a2 = pdw[M][N][s2 + 2], a3 = pdw[M][N][s2 + 3];
        int e0 = h ? a0 : a2, e1 = h ? a1 : a3;
        int r0 = __shfl_xor(e0, 32, 64), r1 = __shfl_xor(e1, 32, 64);
        union { u32x4 u; half8 hv; } bb;
        bb.u[0] = h ? r0 : a0; bb.u[1] = h ? r1 : a1;
        bb.u[2] = h ? a2 : r0; bb.u[3] = h ? a3 : r1;
        of[0][N] = __builtin_amdgcn_mfma_f32_32x32x16_f16(va0, bb.hv, of[0][N], 0, 0, 0);
        of[1][N] = __builtin_amdgcn_mfma_f32_32x32x16_f16(va1, bb.hv, of[1][N], 0, 0, 0);
      }
    }

    if (kt < 15) {
      _Float16* dst = &smem[(kt + 1) & 1][0][0] + soff;
#pragma unroll
      for (int c = 0; c < 4; c++) *(u32x4*)(dst + c * 8) = pf[c];
    }
  }

  // epilogue: normalize, transpose O^T -> O through LDS, coalesced store
  __syncthreads();                       // all waves done with staging buffers
  float inv[2] = {1.0f / l_[0], 1.0f / l_[1]};
  int* OW = (int*)OLds;
#pragma unroll
  for (int N = 0; N < 2; N++) {
    const int q_local = w * 64 + N * 32 + l31;
#pragma unroll
    for (int D = 0; D < 2; D++)
#pragma unroll
      for (int u = 0; u < 8; u++) {
        int v = pack_rtz(of[D][N][2 * u] * inv[N], of[D][N][2 * u + 1] * inv[N]);
        int dwi = 16 * D + 4 * (u >> 1) + (u & 1) + 2 * h;
        OW[q_local * 36 + dwi] = v;
      }
  }
  __syncthreads();
#pragma unroll
  for (int p = 0; p < 8; p++) {
    int q = p * 32 + (tid >> 3), c = tid & 7;
    *(u32x4*)(Oh + (size_t)(b * SEQ + q0 + q) * DM + hh * HD + c * 8) =
        *(const u32x4*)&OLds[q * 72 + c * 8];
  }
}

// ---------------------------------------------------------------------------
// GEMM2: out = Oh[16384x768] @ wprojT^T + bias  (fp32 direct stores)
// ---------------------------------------------------------------------------
__launch_bounds__(256, 3)
__global__ void gemm_proj_kernel(const _Float16* __restrict__ A,
                                 const _Float16* __restrict__ Bt,
                                 const float* __restrict__ bias,
                                 float* __restrict__ out) {
  __shared__ _Float16 sh[20480];     // 2 bufs x (As 128x40 + Bs 128x40)
  const int tid  = threadIdx.x;
  // XCD swizzle: all 6 column tiles of one m0 on one XCD
  const int lin  = blockIdx.x;
  const int xcd  = lin & 7, j = lin >> 3;
  const int ct   = j % 6;
  const int m0   = ((j / 6) * 8 + xcd) * 128;
  const int n0   = ct * 128;
  const int w    = tid >> 6, lane = tid & 63;
  const int quad = lane >> 4, l15 = lane & 15;
  const int wr   = w >> 1, wc = w & 1;

  f32x4 acc[4][4] = {};

  const int e  = tid * 8;
  const int rA = e >> 5;
  const int g8 = e & 31;
  const _Float16* ga = A  + (size_t)(m0 + rA) * 768 + g8;
  const _Float16* gb = Bt + (size_t)(n0 + rA) * 768 + g8;
  const int so = rA * 40 + g8;

  u32x4 pA0 = *(const u32x4*)ga;
  u32x4 pA1 = *(const u32x4*)(ga + 64 * 768);
  u32x4 pB0 = *(const u32x4*)gb;
  u32x4 pB1 = *(const u32x4*)(gb + 64 * 768);
  {
    _Float16* As = sh; _Float16* Bs = sh + 5120;
    *(u32x4*)(As + so) = pA0; *(u32x4*)(As + so + 64 * 40) = pA1;
    *(u32x4*)(Bs + so) = pB0; *(u32x4*)(Bs + so + 64 * 40) = pB1;
  }

  for (int kt = 0; kt < 24; ++kt) {
    __syncthreads();
    if (kt < 23) {
      const int k0 = (kt + 1) * 32;
      pA0 = *(const u32x4*)(ga + k0);
      pA1 = *(const u32x4*)(ga + k0 + 64 * 768);
      pB0 = *(const u32x4*)(gb + k0);
      pB1 = *(const u32x4*)(gb + k0 + 64 * 768);
    }
    const _Float16* As = sh + (kt & 1) * 10240;
    const _Float16* Bs = As + 5120;

    half8 af[4], bf[4];
#pragma unroll
    for (int mi = 0; mi < 4; mi++)
      af[mi] = *(const half8*)&As[(wr * 64 + mi * 16 + l15) * 40 + quad * 8];
#pragma unroll
    for (int ni = 0; ni < 4; ni++)
      bf[ni] = *(const half8*)&Bs[(wc * 64 + ni * 16 + l15) * 40 + quad * 8];
#pragma unroll
    for (int mi = 0; mi < 4; mi++)
#pragma unroll
      for (int ni = 0; ni < 4; ni++)
        acc[mi][ni] = __builtin_amdgcn_mfma_f32_16x16x32_f16(
            af[mi], bf[ni], acc[mi][ni], 0, 0, 0);

    if (kt < 23) {
      _Float16* Asn = sh + ((kt + 1) & 1) * 10240;
      _Float16* Bsn = Asn + 5120;
      *(u32x4*)(Asn + so) = pA0; *(u32x4*)(Asn + so + 64 * 40) = pA1;
      *(u32x4*)(Bsn + so) = pB0; *(u32x4*)(Bsn + so + 64 * 40) = pB1;
    }
  }

  float bcol[4];
#pragma unroll
  for (int ni = 0; ni < 4; ni++)
    bcol[ni] = bias[n0 + wc * 64 + ni * 16 + l15];
#pragma unroll
  for (int mi = 0; mi < 4; mi++)
#pragma unroll
    for (int ni = 0; ni < 4; ni++) {
      int col = n0 + wc * 64 + ni * 16 + l15;
      int row = m0 + wr * 64 + mi * 16 + quad * 4;
#pragma unroll
      for (int r = 0; r < 4; r++)
        out[(size_t)(row + r) * 768 + col] = acc[mi][ni][r] + bcol[ni];
    }
}

// ---------------------------------------------------------------------------
// launch
// ---------------------------------------------------------------------------
extern "C" void kernel_launch(void* const* d_in, const int* in_sizes, int n_in,
                              void* d_out, int out_size, void* d_ws, size_t ws_size,
                              hipStream_t stream) {
  const float* x      = (const float*)d_in[0];
  const float* w_qkv  = (const float*)d_in[1];
  const float* b_qkv  = (const float*)d_in[2];
  const float* w_proj = (const float*)d_in[3];
  const float* b_proj = (const float*)d_in[4];
  float* out = (float*)d_out;

  char* ws = (char*)d_ws;
  _Float16* xh     = (_Float16*)(ws);
  _Float16* wqkvT  = (_Float16*)(ws + 25165824);
  _Float16* wprojT = (_Float16*)(ws + 28704768);
  _Float16* Qp     = (_Float16*)(ws + 29884416);
  _Float16* Kp     = (_Float16*)(ws + 55050240);
  _Float16* VTp    = (_Float16*)(ws + 80216064);
  _Float16* Ohp    = (_Float16*)(ws + 105381888);
  // total: 130547712 B (~125 MB)

  cvt_x_kernel<<<dim3(3145728 / 256), 256, 0, stream>>>(x, xh, 3145728);
  cvt_wt2_kernel<<<dim3(24, 96), 256, 0, stream>>>(w_qkv, wqkvT, w_proj, wprojT);
  gemm_qkv_kernel<<<dim3(2304), 256, 0, stream>>>(xh, wqkvT, b_qkv, Qp, Kp, VTp);
  attn_kernel<<<dim3(768), 256, 0, stream>>>(Qp, Kp, VTp, Ohp);
  gemm_proj_kernel<<<dim3(768), 256, 0, stream>>>(Ohp, wprojT, b_proj, out);
}